// Round 7
// baseline (42.728 us; speedup 1.0000x reference)
//
#include <hip/hip_runtime.h>
#include <math.h>

#define NB 8
#define N_OP 1000
#define N_MA 64
#define IN_DST 64
#define DD 128
#define NEG_SLOPE 0.2f
#define CHUNK 64
#define NCHUNK 16     // 16*64 = 1024 >= 1000 (tail zero-padded)
#define HSTR 132      // H row stride in floats; 16B-aligned, breaks bank aliasing

__device__ __forceinline__ float lrelu(float x) { return x >= 0.f ? x : NEG_SLOPE * x; }

__device__ __forceinline__ float wave_sum(float v) {
    for (int off = 32; off; off >>= 1) v += __shfl_xor(v, off, 64);
    return v;
}

// One block per (b, m-pair): fully independent -> single dispatch, no grid sync.
__global__ __launch_bounds__(256) void gat_fused(
    const float* __restrict__ h_src, const float* __restrict__ h_dst,
    const float* __restrict__ edge_feat, const int* __restrict__ adj,
    const float* __restrict__ W_src, const float* __restrict__ W_dst,
    const float* __restrict__ W_edge, const float* __restrict__ attn_l,
    const float* __restrict__ attn_r, float* __restrict__ out) {
    __shared__ float H_l[CHUNK][HSTR];      // 33.8 KB
    __shared__ float ef_l[2][1024];         // 8 KB
    __shared__ float aj_l[2][1024];         // 8 KB
    __shared__ float Sred[8][2][DD];        // 8 KB
    __shared__ float u_l[DD];
    __shared__ float el_l[CHUNK];
    __shared__ float p_l[2][CHUNK];
    __shared__ float fd_l[2][DD];
    __shared__ float S_l[2][DD];
    __shared__ float er_l[2];
    __shared__ float red4[4];
    __shared__ float redz[2][2], redse[2][2];

    int blk = blockIdx.x;
    int b = blk & 7, mg = blk >> 3;   // same-b blocks -> same XCD (L2 locality heuristic)
    int m0 = mg * 2;
    int t = threadIdx.x;
    int lane = t & 63, w = t >> 6;

    // c_we = dot(W_edge, attn_l): redundant per wave (one-time, cheap)
    float cwe;
    {
        float part = W_edge[lane] * attn_l[lane] + W_edge[lane + 64] * attn_l[lane + 64];
        cwe = wave_sum(part);
    }

    // prefetch this block's two adj/ef columns into LDS (zero tail o>=1000)
    for (int idx = t; idx < 2048; idx += 256) {
        int o = idx >> 1, ml = idx & 1;
        float ef = 0.f, aj = 0.f;
        if (o < N_OP) {
            size_t g = (size_t)(b * N_OP + o) * N_MA + m0 + ml;
            ef = edge_feat[g];
            aj = adj[g] ? 1.f : 0.f;
        }
        ef_l[ml][o] = ef;
        aj_l[ml][o] = aj;
    }

    // u[i] = dot(W_src[i,:], attn_l): thread-pair parallel (64 FMA each + 1 shfl)
    {
        int i = t >> 1, g2 = t & 1;
        const float* wr = W_src + i * DD + g2 * 64;
        const float* al = attn_l + g2 * 64;
        float part = 0.f;
        #pragma unroll 8
        for (int q = 0; q < 64; ++q) part += wr[q] * al[q];
        part += __shfl_xor(part, 1, 64);
        if (g2 == 0) u_l[i] = part;
    }

    // fd rows (2) + er: thread (ml, d), coalesced W_dst columns
    {
        int d = t & 127, ml = t >> 7;
        const float* hd = h_dst + (size_t)(b * N_MA + m0 + ml) * IN_DST;
        float fa = 0.f;
        #pragma unroll 8
        for (int k = 0; k < IN_DST; ++k) fa += hd[k] * W_dst[k * DD + d];
        fd_l[ml][d] = fa;
        float part = fa * attn_r[d];
        part = wave_sum(part);
        if (lane == 0) red4[w] = part;
    }
    __syncthreads();
    if (t < 2) er_l[t] = red4[2 * t] + red4[2 * t + 1];
    __syncthreads();

    float er0 = er_l[0], er1 = er_l[1];

    float acc0[4] = {0.f, 0.f, 0.f, 0.f};
    float acc1[4] = {0.f, 0.f, 0.f, 0.f};
    float z_reg = 0.f, se_reg = 0.f;
    int i4 = t & 31, rg = t >> 5;

    for (int c = 0; c < NCHUNK; ++c) {
        int o0 = c * CHUNK;
        // stage 64 rows of h_src[b] (coalesced float4; OOB rows zeroed)
        #pragma unroll
        for (int s = 0; s < 8; ++s) {
            int flat = s * 256 + t;          // 64 rows x 32 float4 slots
            int row = flat >> 5, col = (flat & 31) * 4;
            float4 hv = make_float4(0.f, 0.f, 0.f, 0.f);
            int o = o0 + row;
            if (o < N_OP)
                hv = *reinterpret_cast<const float4*>(
                    h_src + (size_t)(b * N_OP + o) * DD + col);
            *reinterpret_cast<float4*>(&H_l[row][col]) = hv;
        }
        __syncthreads();

        // el[r] = dot(H[r,:], u): 4 threads/row, stride-4 interleave (2-way banks)
        {
            int r = t >> 2, sub = t & 3;
            float part = 0.f;
            #pragma unroll 8
            for (int qq = 0; qq < 32; ++qq) {
                int q = sub + 4 * qq;
                part += H_l[r][q] * u_l[q];
            }
            part += __shfl_xor(part, 1, 64);
            part += __shfl_xor(part, 2, 64);
            if (sub == 0) el_l[r] = part;
        }
        __syncthreads();

        // p[r][ml] (M=0 softmax numerators; adj=0 -> p=0 via multiplier)
        if (t < 128) {
            int r = t >> 1, ml = t & 1;
            int o = o0 + r;
            float ef = ef_l[ml][o], aj = aj_l[ml][o];
            float er_m = ml ? er1 : er0;
            float vv = lrelu(el_l[r] + er_m + ef * cwe);
            float p = aj * __expf(vv);
            p_l[ml][r] = p;
            z_reg += p;
            se_reg += p * ef;
        }
        __syncthreads();

        // S accumulation: thread (i4, rg) owns i = i4*4..+3, rows rg*8..+7
        #pragma unroll
        for (int rr = 0; rr < 8; ++rr) {
            int r = rg * 8 + rr;
            float4 hv = *reinterpret_cast<const float4*>(&H_l[r][i4 * 4]);
            float p0 = p_l[0][r], p1 = p_l[1][r];
            acc0[0] += p0 * hv.x; acc0[1] += p0 * hv.y;
            acc0[2] += p0 * hv.z; acc0[3] += p0 * hv.w;
            acc1[0] += p1 * hv.x; acc1[1] += p1 * hv.y;
            acc1[2] += p1 * hv.z; acc1[3] += p1 * hv.w;
        }
        __syncthreads();   // guards H_l/p_l overwrite next chunk
    }

    // z/se: reduce over r (keep ml parity; lanes 0/1 end with totals per wave)
    if (t < 128) {
        float zz = z_reg, ss = se_reg;
        #pragma unroll
        for (int off = 2; off <= 32; off <<= 1) {
            zz += __shfl_xor(zz, off, 64);
            ss += __shfl_xor(ss, off, 64);
        }
        if (lane < 2) { redz[lane][w] = zz; redse[lane][w] = ss; }
    }
    // S partials -> LDS
    *reinterpret_cast<float4*>(&Sred[rg][0][i4 * 4]) =
        make_float4(acc0[0], acc0[1], acc0[2], acc0[3]);
    *reinterpret_cast<float4*>(&Sred[rg][1][i4 * 4]) =
        make_float4(acc1[0], acc1[1], acc1[2], acc1[3]);
    __syncthreads();

    // final S
    {
        int d = t & 127, ml = t >> 7;
        float sv = 0.f;
        #pragma unroll
        for (int g = 0; g < 8; ++g) sv += Sred[g][ml][d];
        S_l[ml][d] = sv;
    }
    __syncthreads();

    // bsrc = S @ W_src (coalesced W_src, broadcast S) + epilogue
    {
        int d = t & 127, ml = t >> 7;
        const float* sl = S_l[ml];
        float acc = 0.f;
        #pragma unroll 8
        for (int i = 0; i < DD; ++i) acc += sl[i] * W_src[i * DD + d];
        float er_m = ml ? er1 : er0;
        float p_kk = __expf(lrelu(2.f * er_m));
        float Z = redz[ml][0] + redz[ml][1] + p_kk;
        float SE = redse[ml][0] + redse[ml][1];
        float invZ = 1.f / Z;
        float val = W_edge[d] * (SE * invZ) + acc * invZ +
                    fd_l[ml][d] * (p_kk * invZ);
        out[(size_t)(b * N_MA + m0 + ml) * DD + d] = 1.f / (1.f + __expf(-val));
    }
}

extern "C" void kernel_launch(void* const* d_in, const int* in_sizes, int n_in,
                              void* d_out, int out_size, void* d_ws, size_t ws_size,
                              hipStream_t stream) {
    const float* h_src = (const float*)d_in[0];
    const float* h_dst = (const float*)d_in[1];
    const float* edge_feat = (const float*)d_in[2];
    const int* adj = (const int*)d_in[3];
    const float* W_src = (const float*)d_in[4];
    const float* W_dst = (const float*)d_in[5];
    const float* W_edge = (const float*)d_in[6];
    const float* attn_l = (const float*)d_in[7];
    const float* attn_r = (const float*)d_in[8];
    float* out = (float*)d_out;

    gat_fused<<<NB * N_MA / 2, 256, 0, stream>>>(
        h_src, h_dst, edge_feat, adj, W_src, W_dst, W_edge, attn_l, attn_r, out);
}

// Round 8
// 26.171 us; speedup vs baseline: 1.6327x; 1.6327x over previous
//
#include <hip/hip_runtime.h>
#include <math.h>

#define NB 8
#define N_OP 1000
#define N_MA 64
#define IN_DST 64
#define DD 128
#define NEG_SLOPE 0.2f
#define TILE_O 32
#define NTILE 32   // 32*32 = 1024 >= 1000 (tail guarded)
#define HPAD 132   // H tile stride: breaks bank aliasing on the el reduce

__device__ __forceinline__ float lrelu(float x) { return x >= 0.f ? x : NEG_SLOPE * x; }

__device__ __forceinline__ float wave_sum(float v) {
    for (int off = 32; off; off >>= 1) v += __shfl_xor(v, off, 64);
    return v;
}

// K1: per (b, o-tile). Self-contained: computes c_we/u/v/er/el in-block with
// thread-parallel reductions, then masked exp stats (M=0; logits bounded ~14,
// safe in f32) and partial contraction S_part[b,ti,m,i] = sum_o p[o,m]*H[o,i].
__global__ __launch_bounds__(256) void ab2_kernel(
    const float* __restrict__ h_src, const float* __restrict__ h_dst,
    const float* __restrict__ edge_feat, const int* __restrict__ adj,
    const float* __restrict__ W_src, const float* __restrict__ W_dst,
    const float* __restrict__ W_edge, const float* __restrict__ attn_l,
    const float* __restrict__ attn_r, float* __restrict__ S_part,
    float* __restrict__ zpart, float* __restrict__ separt) {
    __shared__ float H_l[TILE_O][HPAD];    // 16.9 KB
    __shared__ float P_l[TILE_O][N_MA];    // 8 KB
    __shared__ float u_l[DD];
    __shared__ float v_l[IN_DST];
    __shared__ float er_l[N_MA];
    __shared__ float el_l[TILE_O];
    __shared__ float redz[4][64], redse[4][64];

    int blk = blockIdx.x;               // 0..255
    int b = blk >> 5, ti = blk & 31;
    int o0 = ti * TILE_O;
    int nrows = min(TILE_O, N_OP - o0); // 32 (8 for ti==31)
    int t = threadIdx.x;
    int lane = t & 63, w = t >> 6;

    // stage H tile (coalesced float4); zero OOB rows
    #pragma unroll
    for (int c = 0; c < 4; ++c) {
        int flat = c * 256 + t;          // 1024 float4 slots = 32 rows x 32
        int row = flat >> 5, col = (flat & 31) * 4;
        float4 hv = make_float4(0.f, 0.f, 0.f, 0.f);
        if (row < nrows)
            hv = *reinterpret_cast<const float4*>(
                h_src + ((size_t)(b * N_OP + o0 + row) * DD + col));
        *reinterpret_cast<float4*>(&H_l[row][col]) = hv;
    }

    // c_we = dot(W_edge, attn_l): per-lane redundant (one wave_sum)
    float al0 = attn_l[lane], al1 = attn_l[lane + 64];
    float cwe = wave_sum(W_edge[lane] * al0 + W_edge[lane + 64] * al1);

    // u[i] = dot(W_src[i,:], attn_l): 2 threads/row x 64 FMA (parallel)
    {
        int i = t >> 1, g2 = t & 1;
        const float* wr = W_src + i * DD + g2 * 64;
        const float* al = attn_l + g2 * 64;
        float part = 0.f;
        #pragma unroll 16
        for (int q = 0; q < 64; ++q) part += wr[q] * al[q];
        part += __shfl_xor(part, 1, 64);
        if (g2 == 0) u_l[i] = part;
    }
    // v[k] = dot(W_dst[k,:], attn_r): 4 threads/k x 32 FMA
    {
        int k = t >> 2, q4 = t & 3;
        const float* wd = W_dst + k * DD + q4 * 32;
        const float* ar = attn_r + q4 * 32;
        float part = 0.f;
        #pragma unroll 8
        for (int q = 0; q < 32; ++q) part += wd[q] * ar[q];
        part += __shfl_xor(part, 1, 64);
        part += __shfl_xor(part, 2, 64);
        if (q4 == 0) v_l[k] = part;
    }
    __syncthreads();  // H_l, u_l, v_l ready

    // er[m] = dot(h_dst[b,m,:], v): 4 threads/m x 16 FMA
    {
        int m = t >> 2, q4 = t & 3;
        const float* hd = h_dst + (size_t)(b * N_MA + m) * IN_DST + q4 * 16;
        float part = 0.f;
        #pragma unroll
        for (int q = 0; q < 16; ++q) part += hd[q] * v_l[q4 * 16 + q];
        part += __shfl_xor(part, 1, 64);
        part += __shfl_xor(part, 2, 64);
        if (q4 == 0) er_l[m] = part;
    }
    // el[r] = dot(H[r,:], u): 8 threads/row x 16 FMA (OOB rows give 0)
    {
        int r = t >> 3, sub = t & 7;
        float part = 0.f;
        #pragma unroll
        for (int q = 0; q < 16; ++q)
            part += H_l[r][sub + 8 * q] * u_l[sub + 8 * q];
        part += __shfl_xor(part, 1, 64);
        part += __shfl_xor(part, 2, 64);
        part += __shfl_xor(part, 4, 64);
        if (sub == 0) el_l[r] = part;
    }
    __syncthreads();  // er_l, el_l ready

    // phase 1: p + per-tile stats (coalesced adj/ef rows)
    int m = t & 63, og = t >> 6;
    float er_bm = er_l[m];
    float z = 0.f, se = 0.f;
    for (int r = og; r < TILE_O; r += 4) {
        float p = 0.f;
        if (r < nrows) {
            size_t eidx = (size_t)(b * N_OP + o0 + r) * N_MA + m;
            if (adj[eidx]) {
                float efv = edge_feat[eidx];
                float v = lrelu(el_l[r] + er_bm + efv * cwe);
                p = __expf(v);
                z += p;
                se += p * efv;
            }
        }
        P_l[r][m] = p;
    }
    redz[og][m] = z;
    redse[og][m] = se;
    __syncthreads();

    if (t < 64) {
        zpart[ti * 512 + b * N_MA + t] =
            redz[0][t] + redz[1][t] + redz[2][t] + redz[3][t];
    } else if (t < 128) {
        int mm = t - 64;
        separt[ti * 512 + b * N_MA + mm] =
            redse[0][mm] + redse[1][mm] + redse[2][mm] + redse[3][mm];
    }

    // phase 2: S_part[m][i] = sum_k P_l[k][m] * H_l[k][i]
    int i4 = t & 31, mg = t >> 5;
    float acc[8][4];
    #pragma unroll
    for (int a = 0; a < 8; ++a)
        #pragma unroll
        for (int c = 0; c < 4; ++c) acc[a][c] = 0.f;

    for (int k = 0; k < TILE_O; ++k) {
        float4 hv = *reinterpret_cast<const float4*>(&H_l[k][i4 * 4]);
        float4 pa = *reinterpret_cast<const float4*>(&P_l[k][mg * 8]);
        float4 pb = *reinterpret_cast<const float4*>(&P_l[k][mg * 8 + 4]);
        float hh[4] = {hv.x, hv.y, hv.z, hv.w};
        float pp[8] = {pa.x, pa.y, pa.z, pa.w, pb.x, pb.y, pb.z, pb.w};
        #pragma unroll
        for (int mm = 0; mm < 8; ++mm)
            #pragma unroll
            for (int ii = 0; ii < 4; ++ii)
                acc[mm][ii] += pp[mm] * hh[ii];
    }

    #pragma unroll
    for (int mm = 0; mm < 8; ++mm) {
        size_t off = ((size_t)(b * NTILE + ti) * N_MA + mg * 8 + mm) * DD + i4 * 4;
        *reinterpret_cast<float4*>(S_part + off) =
            make_float4(acc[mm][0], acc[mm][1], acc[mm][2], acc[mm][3]);
    }
}

// K2: per (b,m): sum tile partials; recompute feat_dst row + er in-block
// (R2's proven c_fused pattern); W_src matvec; sigmoid epilogue.
__global__ __launch_bounds__(256) void c2_kernel(
    const float* __restrict__ S_part, const float* __restrict__ zpart,
    const float* __restrict__ separt, const float* __restrict__ h_dst,
    const float* __restrict__ W_dst, const float* __restrict__ W_src,
    const float* __restrict__ W_edge, const float* __restrict__ attn_r,
    float* __restrict__ out) {
    __shared__ float Sp[2][DD];
    __shared__ float Fp[2][DD];
    __shared__ float Wp[2][DD];
    __shared__ float S_l[DD];
    __shared__ float fd_l[DD];
    __shared__ float hd_l[IN_DST];
    __shared__ float sZ, sSE, sER;

    int bm = blockIdx.x;
    int b = bm >> 6, m = bm & 63;
    int t = threadIdx.x;
    int lane = t & 63, w = t >> 6;
    int i = t & 127, h = t >> 7;

    if (t < IN_DST) hd_l[t] = h_dst[(size_t)bm * IN_DST + t];

    if (w == 0) {
        float vz = (lane < NTILE) ? zpart[lane * 512 + bm] : 0.f;
        vz = wave_sum(vz);
        if (lane == 0) sZ = vz;
    } else if (w == 1) {
        float vs = (lane < NTILE) ? separt[lane * 512 + bm] : 0.f;
        vs = wave_sum(vs);
        if (lane == 0) sSE = vs;
    }

    float ps = 0.f;
    #pragma unroll
    for (int q = 0; q < NTILE / 2; ++q) {
        int ti = h * (NTILE / 2) + q;
        ps += S_part[((size_t)(b * NTILE + ti) * N_MA + m) * DD + i];
    }
    Sp[h][i] = ps;
    __syncthreads();  // hd_l, Sp, stats ready

    if (t < DD) S_l[t] = Sp[0][t] + Sp[1][t];
    float fa = 0.f;
    #pragma unroll 8
    for (int k = h * 32; k < h * 32 + 32; ++k) fa += hd_l[k] * W_dst[k * DD + i];
    Fp[h][i] = fa;
    __syncthreads();  // S_l, Fp ready

    if (t < DD) fd_l[t] = Fp[0][t] + Fp[1][t];
    float acc = 0.f;
    #pragma unroll 8
    for (int q = 0; q < 64; ++q) {
        int ii = h * 64 + q;
        acc += S_l[ii] * W_src[ii * DD + i];
    }
    Wp[h][i] = acc;
    __syncthreads();  // fd_l, Wp ready

    if (w == 0) {
        float e = fd_l[lane] * attn_r[lane] + fd_l[lane + 64] * attn_r[lane + 64];
        e = wave_sum(e);
        if (lane == 0) sER = e;
    }
    __syncthreads();

    if (t < DD) {
        float p_kk = __expf(lrelu(2.f * sER));
        float Z = sZ + p_kk;
        float invZ = 1.f / Z;
        float bsrc = (Wp[0][i] + Wp[1][i]) * invZ;
        float val = W_edge[i] * (sSE * invZ) + bsrc + fd_l[i] * (p_kk * invZ);
        out[(size_t)bm * DD + i] = 1.f / (1.f + __expf(-val));
    }
}

extern "C" void kernel_launch(void* const* d_in, const int* in_sizes, int n_in,
                              void* d_out, int out_size, void* d_ws, size_t ws_size,
                              hipStream_t stream) {
    const float* h_src = (const float*)d_in[0];
    const float* h_dst = (const float*)d_in[1];
    const float* edge_feat = (const float*)d_in[2];
    const int* adj = (const int*)d_in[3];
    const float* W_src = (const float*)d_in[4];
    const float* W_dst = (const float*)d_in[5];
    const float* W_edge = (const float*)d_in[6];
    const float* attn_l = (const float*)d_in[7];
    const float* attn_r = (const float*)d_in[8];
    float* out = (float*)d_out;

    float* ws = (float*)d_ws;
    float* zpart = ws;                 // 32*512 = 16384
    float* separt = ws + 16384;        // 16384
    float* S_part = ws + 32768;        // 8*32*64*128 = 2097152

    ab2_kernel<<<NB * NTILE, 256, 0, stream>>>(
        h_src, h_dst, edge_feat, adj, W_src, W_dst, W_edge, attn_l, attn_r,
        S_part, zpart, separt);
    c2_kernel<<<NB * N_MA, 256, 0, stream>>>(
        S_part, zpart, separt, h_dst, W_dst, W_src, W_edge, attn_r, out);
}

// Round 9
// 25.186 us; speedup vs baseline: 1.6965x; 1.0391x over previous
//
#include <hip/hip_runtime.h>
#include <math.h>

#define NB 8
#define N_OP 1000
#define N_MA 64
#define IN_DST 64
#define DD 128
#define NEG_SLOPE 0.2f
#define TILE_O 32
#define NTILE 32   // 32*32 = 1024 >= 1000 (tail guarded)
#define HPAD 132   // padded stride: breaks bank aliasing on strided LDS reduces

__device__ __forceinline__ float lrelu(float x) { return x >= 0.f ? x : NEG_SLOPE * x; }

__device__ __forceinline__ float wave_sum(float v) {
    for (int off = 32; off; off >>= 1) v += __shfl_xor(v, off, 64);
    return v;
}

// K1: per (b, o-tile). Self-contained with COALESCED in-block recompute:
// u/v via LDS-staged W chunks (float4 coalesced), er via L1-hot h_dst reads,
// el from the staged H tile. Then masked exp stats (M=0; logits bounded ~14,
// safe in f32) and partial contraction S_part[b,ti,m,i] = sum_o p[o,m]*H[o,i].
__global__ __launch_bounds__(256) void ab3_kernel(
    const float* __restrict__ h_src, const float* __restrict__ h_dst,
    const float* __restrict__ edge_feat, const int* __restrict__ adj,
    const float* __restrict__ W_src, const float* __restrict__ W_dst,
    const float* __restrict__ W_edge, const float* __restrict__ attn_l,
    const float* __restrict__ attn_r, float* __restrict__ S_part,
    float* __restrict__ zpart, float* __restrict__ separt) {
    __shared__ float H_l[TILE_O][HPAD];    // 16.9 KB
    __shared__ float Wc[32][HPAD];         // 16.9 KB (W_src/W_dst chunk staging)
    __shared__ float P_l[TILE_O][N_MA];    // 8 KB
    __shared__ float al_l[DD], ar_l[DD];
    __shared__ float u_l[DD];
    __shared__ float v_l[IN_DST];
    __shared__ float er_l[N_MA];
    __shared__ float el_l[TILE_O];
    __shared__ float redz[4][64], redse[4][64];

    int blk = blockIdx.x;               // 0..255
    int b = blk >> 5, ti = blk & 31;
    int o0 = ti * TILE_O;
    int nrows = min(TILE_O, N_OP - o0); // 32 (8 for ti==31)
    int t = threadIdx.x;
    int lane = t & 63, w = t >> 6;

    // stage attn vectors
    if (t < DD) al_l[t] = attn_l[t];
    else ar_l[t - DD] = attn_r[t - DD];

    // stage H tile (coalesced float4); zero OOB rows
    #pragma unroll
    for (int c = 0; c < 4; ++c) {
        int flat = c * 256 + t;          // 1024 float4 slots = 32 rows x 32
        int row = flat >> 5, col = (flat & 31) * 4;
        float4 hv = make_float4(0.f, 0.f, 0.f, 0.f);
        if (row < nrows)
            hv = *reinterpret_cast<const float4*>(
                h_src + ((size_t)(b * N_OP + o0 + row) * DD + col));
        *reinterpret_cast<float4*>(&H_l[row][col]) = hv;
    }

    // c_we = dot(W_edge, attn_l): coalesced global reads, one wave_sum
    float cwe = wave_sum(W_edge[lane] * attn_l[lane] +
                         W_edge[lane + 64] * attn_l[lane + 64]);

    int il = t >> 3, sub = t & 7;       // 8 threads per reduce output

    // u[i] = dot(W_src[i,:], attn_l): 4 LDS-staged chunks of 32 rows
    for (int cc = 0; cc < 4; ++cc) {
        #pragma unroll
        for (int s = 0; s < 4; ++s) {
            int flat = s * 256 + t;
            int row = flat >> 5, col = (flat & 31) * 4;
            *reinterpret_cast<float4*>(&Wc[row][col]) =
                *reinterpret_cast<const float4*>(
                    W_src + ((size_t)(cc * 32 + row) * DD + col));
        }
        __syncthreads();  // chunk staged (first iteration also fences al_l/ar_l)
        float part = 0.f;
        #pragma unroll
        for (int q = 0; q < 16; ++q)
            part += Wc[il][sub + 8 * q] * al_l[sub + 8 * q];
        part += __shfl_xor(part, 1, 64);
        part += __shfl_xor(part, 2, 64);
        part += __shfl_xor(part, 4, 64);
        if (sub == 0) u_l[cc * 32 + il] = part;
        __syncthreads();  // before overwriting Wc
    }

    // v[k] = dot(W_dst[k,:], attn_r): 2 LDS-staged chunks of 32 rows
    for (int cc = 0; cc < 2; ++cc) {
        #pragma unroll
        for (int s = 0; s < 4; ++s) {
            int flat = s * 256 + t;
            int row = flat >> 5, col = (flat & 31) * 4;
            *reinterpret_cast<float4*>(&Wc[row][col]) =
                *reinterpret_cast<const float4*>(
                    W_dst + ((size_t)(cc * 32 + row) * DD + col));
        }
        __syncthreads();
        float part = 0.f;
        #pragma unroll
        for (int q = 0; q < 16; ++q)
            part += Wc[il][sub + 8 * q] * ar_l[sub + 8 * q];
        part += __shfl_xor(part, 1, 64);
        part += __shfl_xor(part, 2, 64);
        part += __shfl_xor(part, 4, 64);
        if (sub == 0) v_l[cc * 32 + il] = part;
        __syncthreads();
    }

    // er[m] = dot(h_dst[b,m,:], v): 4 threads/m x 16 reads (h_dst[b] is L1-hot)
    {
        int m = t >> 2, q4 = t & 3;
        const float* hd = h_dst + (size_t)(b * N_MA + m) * IN_DST + q4 * 16;
        float part = 0.f;
        #pragma unroll
        for (int q = 0; q < 16; ++q) part += hd[q] * v_l[q4 * 16 + q];
        part += __shfl_xor(part, 1, 64);
        part += __shfl_xor(part, 2, 64);
        if (q4 == 0) er_l[m] = part;
    }
    // el[r] = dot(H[r,:], u): 8 threads/row x 16 FMA (OOB rows give 0)
    {
        int r = t >> 3;
        float part = 0.f;
        #pragma unroll
        for (int q = 0; q < 16; ++q)
            part += H_l[r][sub + 8 * q] * u_l[sub + 8 * q];
        part += __shfl_xor(part, 1, 64);
        part += __shfl_xor(part, 2, 64);
        part += __shfl_xor(part, 4, 64);
        if (sub == 0) el_l[r] = part;
    }
    __syncthreads();  // er_l, el_l ready

    // phase 1: p + per-tile stats (coalesced adj/ef rows)
    int m = t & 63, og = t >> 6;
    float er_bm = er_l[m];
    float z = 0.f, se = 0.f;
    for (int r = og; r < TILE_O; r += 4) {
        float p = 0.f;
        if (r < nrows) {
            size_t eidx = (size_t)(b * N_OP + o0 + r) * N_MA + m;
            if (adj[eidx]) {
                float efv = edge_feat[eidx];
                float v = lrelu(el_l[r] + er_bm + efv * cwe);
                p = __expf(v);
                z += p;
                se += p * efv;
            }
        }
        P_l[r][m] = p;
    }
    redz[og][m] = z;
    redse[og][m] = se;
    __syncthreads();

    if (t < 64) {
        zpart[ti * 512 + b * N_MA + t] =
            redz[0][t] + redz[1][t] + redz[2][t] + redz[3][t];
    } else if (t < 128) {
        int mm = t - 64;
        separt[ti * 512 + b * N_MA + mm] =
            redse[0][mm] + redse[1][mm] + redse[2][mm] + redse[3][mm];
    }

    // phase 2: S_part[m][i] = sum_k P_l[k][m] * H_l[k][i]
    int i4 = t & 31, mg = t >> 5;
    float acc[8][4];
    #pragma unroll
    for (int a = 0; a < 8; ++a)
        #pragma unroll
        for (int c = 0; c < 4; ++c) acc[a][c] = 0.f;

    for (int k = 0; k < TILE_O; ++k) {
        float4 hv = *reinterpret_cast<const float4*>(&H_l[k][i4 * 4]);
        float4 pa = *reinterpret_cast<const float4*>(&P_l[k][mg * 8]);
        float4 pb = *reinterpret_cast<const float4*>(&P_l[k][mg * 8 + 4]);
        float hh[4] = {hv.x, hv.y, hv.z, hv.w};
        float pp[8] = {pa.x, pa.y, pa.z, pa.w, pb.x, pb.y, pb.z, pb.w};
        #pragma unroll
        for (int mm = 0; mm < 8; ++mm)
            #pragma unroll
            for (int ii = 0; ii < 4; ++ii)
                acc[mm][ii] += pp[mm] * hh[ii];
    }

    #pragma unroll
    for (int mm = 0; mm < 8; ++mm) {
        size_t off = ((size_t)(b * NTILE + ti) * N_MA + mg * 8 + mm) * DD + i4 * 4;
        *reinterpret_cast<float4*>(S_part + off) =
            make_float4(acc[mm][0], acc[mm][1], acc[mm][2], acc[mm][3]);
    }
}

// K2: per (b,m): sum tile partials; recompute feat_dst row + er in-block
// (coalesced W_dst column reads); W_src matvec; sigmoid epilogue.
__global__ __launch_bounds__(256) void c2_kernel(
    const float* __restrict__ S_part, const float* __restrict__ zpart,
    const float* __restrict__ separt, const float* __restrict__ h_dst,
    const float* __restrict__ W_dst, const float* __restrict__ W_src,
    const float* __restrict__ W_edge, const float* __restrict__ attn_r,
    float* __restrict__ out) {
    __shared__ float Sp[2][DD];
    __shared__ float Fp[2][DD];
    __shared__ float Wp[2][DD];
    __shared__ float S_l[DD];
    __shared__ float fd_l[DD];
    __shared__ float hd_l[IN_DST];
    __shared__ float sZ, sSE, sER;

    int bm = blockIdx.x;
    int b = bm >> 6, m = bm & 63;
    int t = threadIdx.x;
    int lane = t & 63, w = t >> 6;
    int i = t & 127, h = t >> 7;

    if (t < IN_DST) hd_l[t] = h_dst[(size_t)bm * IN_DST + t];

    if (w == 0) {
        float vz = (lane < NTILE) ? zpart[lane * 512 + bm] : 0.f;
        vz = wave_sum(vz);
        if (lane == 0) sZ = vz;
    } else if (w == 1) {
        float vs = (lane < NTILE) ? separt[lane * 512 + bm] : 0.f;
        vs = wave_sum(vs);
        if (lane == 0) sSE = vs;
    }

    float ps = 0.f;
    #pragma unroll
    for (int q = 0; q < NTILE / 2; ++q) {
        int ti = h * (NTILE / 2) + q;
        ps += S_part[((size_t)(b * NTILE + ti) * N_MA + m) * DD + i];
    }
    Sp[h][i] = ps;
    __syncthreads();  // hd_l, Sp, stats ready

    if (t < DD) S_l[t] = Sp[0][t] + Sp[1][t];
    float fa = 0.f;
    #pragma unroll 8
    for (int k = h * 32; k < h * 32 + 32; ++k) fa += hd_l[k] * W_dst[k * DD + i];
    Fp[h][i] = fa;
    __syncthreads();  // S_l, Fp ready

    if (t < DD) fd_l[t] = Fp[0][t] + Fp[1][t];
    float acc = 0.f;
    #pragma unroll 8
    for (int q = 0; q < 64; ++q) {
        int ii = h * 64 + q;
        acc += S_l[ii] * W_src[ii * DD + i];
    }
    Wp[h][i] = acc;
    __syncthreads();  // fd_l, Wp ready

    if (w == 0) {
        float e = fd_l[lane] * attn_r[lane] + fd_l[lane + 64] * attn_r[lane + 64];
        e = wave_sum(e);
        if (lane == 0) sER = e;
    }
    __syncthreads();

    if (t < DD) {
        float p_kk = __expf(lrelu(2.f * sER));
        float Z = sZ + p_kk;
        float invZ = 1.f / Z;
        float bsrc = (Wp[0][i] + Wp[1][i]) * invZ;
        float val = W_edge[i] * (sSE * invZ) + bsrc + fd_l[i] * (p_kk * invZ);
        out[(size_t)bm * DD + i] = 1.f / (1.f + __expf(-val));
    }
}

extern "C" void kernel_launch(void* const* d_in, const int* in_sizes, int n_in,
                              void* d_out, int out_size, void* d_ws, size_t ws_size,
                              hipStream_t stream) {
    const float* h_src = (const float*)d_in[0];
    const float* h_dst = (const float*)d_in[1];
    const float* edge_feat = (const float*)d_in[2];
    const int* adj = (const int*)d_in[3];
    const float* W_src = (const float*)d_in[4];
    const float* W_dst = (const float*)d_in[5];
    const float* W_edge = (const float*)d_in[6];
    const float* attn_l = (const float*)d_in[7];
    const float* attn_r = (const float*)d_in[8];
    float* out = (float*)d_out;

    float* ws = (float*)d_ws;
    float* zpart = ws;                 // 32*512 = 16384
    float* separt = ws + 16384;        // 16384
    float* S_part = ws + 32768;        // 8*32*64*128 = 2097152

    ab3_kernel<<<NB * NTILE, 256, 0, stream>>>(
        h_src, h_dst, edge_feat, adj, W_src, W_dst, W_edge, attn_l, attn_r,
        S_part, zpart, separt);
    c2_kernel<<<NB * N_MA, 256, 0, stream>>>(
        S_part, zpart, separt, h_dst, W_dst, W_src, W_edge, attn_r, out);
}